// Round 9
// baseline (67.946 us; speedup 1.0000x reference)
//
#include <hip/hip_runtime.h>
#include <math.h>

// NoisyTopKGating via fp16x2-split MFMA. LDS-broadcast staging via global_load_lds,
// counted vmcnt (T3+T4), K=64 per iteration (one barrier per TWO k-steps),
// NBUF=3 x 48KB buffers, stage issued AFTER the barrier (race-free at distance 2).
// BM=64 rows/block, 512 threads (8 waves: 2 rg x 4 cg), 256 blocks (1/CU).
// out layout (f32 flat): weights [N,2] @0, indices-as-float [N,2] @32768, clean [N,64] @65536.
// d_ws: Bh packed frags (512KB) @0, Bl packed frags (512KB) @+262144 f16.
// Packed layout (f16 units): [(kc*8 + cg*2 + cf)*512 + lane*8 + j]
//   col = cg*32 + cf*16 + (lane&15),  k = kc*32 + (lane>>4)*8 + j.

constexpr int NROWS = 16384;
constexpr int DDIM  = 2048;
constexpr int EDIM  = 64;
constexpr int BM    = 64;             // rows per block
constexpr int NIT   = 32;             // iterations of K=64 (2 k-steps each)
constexpr int LSTR  = 132;            // epilogue LDS stride (floats)
constexpr int IDX_OFF   = NROWS * 2;
constexpr int CLEAN_OFF = NROWS * 4;
constexpr size_t WPACK = 262144;      // f16 elements per packed matrix (128*2048)
// buffer: X [2 halves][64 rows][128B] 16KB @0, Bh [2][8KB] @16384, Bl [2][8KB] @32768
constexpr int BUFSZ = 49152;
constexpr int NBUF  = 3;              // 144KB LDS total (dynamic)

typedef _Float16 f16x8 __attribute__((ext_vector_type(8)));
typedef float    f32x4 __attribute__((ext_vector_type(4)));

__device__ __forceinline__ float softplus_f(float z) {
    return fmaxf(z, 0.0f) + log1pf(expf(-fabsf(z)));
}

__device__ __forceinline__ void gload16(const void* g, void* l) {
    __builtin_amdgcn_global_load_lds(
        (const __attribute__((address_space(1))) unsigned int*)g,
        (__attribute__((address_space(3))) unsigned int*)l, 16, 0, 0);
}

// ---------- pre-kernel: split + pack weights into frag-ordered hi/lo ----------
__global__ __launch_bounds__(256) void split_w_kernel(
    const float* __restrict__ Wg, const float* __restrict__ Wn,
    _Float16* __restrict__ wh, _Float16* __restrict__ wl)
{
    const int t    = blockIdx.x * 256 + threadIdx.x;   // 0..32767
    const int grp  = t >> 6;                           // kc*8 + cg*2 + cf  (0..511)
    const int lane = t & 63;
    const int kc   = grp >> 3;
    const int cg   = (grp >> 1) & 3;
    const int cf   = grp & 1;
    const int col  = cg * 32 + cf * 16 + (lane & 15);
    const int k0   = kc * 32 + (lane >> 4) * 8;
    const float* src = (col < 64) ? &Wg[(size_t)col * DDIM + k0]
                                  : &Wn[(size_t)(col - 64) * DDIM + k0];
    const float4 v0 = *reinterpret_cast<const float4*>(src);
    const float4 v1 = *reinterpret_cast<const float4*>(src + 4);
    float vv[8] = {v0.x, v0.y, v0.z, v0.w, v1.x, v1.y, v1.z, v1.w};
    union { _Float16 h[8]; uint4 u; } hh, ll;
    #pragma unroll
    for (int j = 0; j < 8; ++j) {
        hh.h[j] = (_Float16)vv[j];
        ll.h[j] = (_Float16)((vv[j] - (float)hh.h[j]) * 2048.0f);
    }
    const size_t off = (size_t)grp * 512 + lane * 8;
    *reinterpret_cast<uint4*>(&wh[off]) = hh.u;
    *reinterpret_cast<uint4*>(&wl[off]) = ll.u;
}

__device__ __forceinline__ void split8(const float4 a, const float4 b, f16x8& h, f16x8& l) {
    const float v[8] = {a.x, a.y, a.z, a.w, b.x, b.y, b.z, b.w};
    #pragma unroll
    for (int j = 0; j < 8; ++j) {
        const _Float16 hh = (_Float16)v[j];
        h[j] = hh;
        l[j] = (_Float16)((v[j] - (float)hh) * 2048.0f);
    }
}

// ---------- main fused kernel ----------
__global__ __launch_bounds__(512, 1) void gating_mfma_kernel(
    const float* __restrict__ x,
    const float* __restrict__ noise,
    const _Float16* __restrict__ whp,
    const _Float16* __restrict__ wlp,
    float* __restrict__ out)
{
    extern __shared__ __align__(16) unsigned char smem[];   // NBUF*BUFSZ = 144KB

    const int tid = threadIdx.x;
    const int row_base = blockIdx.x * BM;
    const int lane = tid & 63;
    const int wid  = tid >> 6;           // 0..7
    const int g    = (lane >> 4) & 3;    // k-group
    const int idx  = lane & 15;
    const int rg   = wid >> 2;           // row-group 0..1
    const int cg   = wid & 3;            // col-group 0..3

    // ---- staging addresses ----
    // x: thread stages 16B per 32-k half; LDS dest linear; source pre-swizzled
    const int sr  = tid >> 3;            // row 0..63
    const int sq  = tid & 7;             // 16B slot 0..7
    const int sq2 = sq ^ (sr & 7);
    const float* xsrc = x + (size_t)(row_base + sr) * DDIM + sq2 * 4;
    const char* bhsrc = (const char*)whp + tid * 16;
    const char* blsrc = (const char*)wlp + tid * 16;

    // ---- A-frag read offsets (swizzled): row = rg*32 + rf*16 + idx ----
    // per k-step ks: base ks*8192; per rf two 16B slots (2g, 2g+1)
    int aoff[2][2][2];                   // [ks][rf][j]
    #pragma unroll
    for (int ks = 0; ks < 2; ++ks)
        #pragma unroll
        for (int rf = 0; rf < 2; ++rf) {
            const int row = rg * 32 + rf * 16 + idx;
            #pragma unroll
            for (int j = 0; j < 2; ++j)
                aoff[ks][rf][j] = ks * 8192 + row * 128 + (((g * 2 + j) ^ (row & 7)) << 4);
        }
    // ---- B-frag read offsets ----
    int bhoff[2][2], bloff[2][2];        // [ks][cf]
    #pragma unroll
    for (int ks = 0; ks < 2; ++ks)
        #pragma unroll
        for (int cf = 0; cf < 2; ++cf) {
            bhoff[ks][cf] = 16384 + ks * 8192 + (cg * 2 + cf) * 1024 + lane * 16;
            bloff[ks][cf] = 32768 + ks * 8192 + (cg * 2 + cf) * 1024 + lane * 16;
        }

    f32x4 accm[2][2], accc[2][2];
    #pragma unroll
    for (int rf = 0; rf < 2; ++rf)
        #pragma unroll
        for (int cf = 0; cf < 2; ++cf) { accm[rf][cf] = (f32x4)0.0f; accc[rf][cf] = (f32x4)0.0f; }

    auto stage = [&](int u) {            // u = K64 iteration index; 6 loads
        const int b = (u % NBUF) * BUFSZ;
        gload16(xsrc + u * 64,                      smem + b + tid * 16);            // X half 0
        gload16(xsrc + u * 64 + 32,                 smem + b + 8192 + tid * 16);     // X half 1
        gload16(bhsrc + (size_t)(2 * u) * 8192,     smem + b + 16384 + tid * 16);    // Bh ks0
        gload16(bhsrc + (size_t)(2 * u + 1) * 8192, smem + b + 24576 + tid * 16);    // Bh ks1
        gload16(blsrc + (size_t)(2 * u) * 8192,     smem + b + 32768 + tid * 16);    // Bl ks0
        gload16(blsrc + (size_t)(2 * u + 1) * 8192, smem + b + 40960 + tid * 16);    // Bl ks1
    };

    auto computeStep = [&](int b, int ks) {
        const float4 a00 = *reinterpret_cast<const float4*>(&smem[b + aoff[ks][0][0]]);
        const float4 a01 = *reinterpret_cast<const float4*>(&smem[b + aoff[ks][0][1]]);
        const float4 a10 = *reinterpret_cast<const float4*>(&smem[b + aoff[ks][1][0]]);
        const float4 a11 = *reinterpret_cast<const float4*>(&smem[b + aoff[ks][1][1]]);
        const f16x8 Bh0 = *reinterpret_cast<const f16x8*>(&smem[b + bhoff[ks][0]]);
        const f16x8 Bh1 = *reinterpret_cast<const f16x8*>(&smem[b + bhoff[ks][1]]);
        const f16x8 Bl0 = *reinterpret_cast<const f16x8*>(&smem[b + bloff[ks][0]]);
        const f16x8 Bl1 = *reinterpret_cast<const f16x8*>(&smem[b + bloff[ks][1]]);

        f16x8 Ah0, Al0, Ah1, Al1;
        split8(a00, a01, Ah0, Al0);
        split8(a10, a11, Ah1, Al1);

        accm[0][0] = __builtin_amdgcn_mfma_f32_16x16x32_f16(Ah0, Bh0, accm[0][0], 0, 0, 0);
        accm[0][1] = __builtin_amdgcn_mfma_f32_16x16x32_f16(Ah0, Bh1, accm[0][1], 0, 0, 0);
        accm[1][0] = __builtin_amdgcn_mfma_f32_16x16x32_f16(Ah1, Bh0, accm[1][0], 0, 0, 0);
        accm[1][1] = __builtin_amdgcn_mfma_f32_16x16x32_f16(Ah1, Bh1, accm[1][1], 0, 0, 0);
        accc[0][0] = __builtin_amdgcn_mfma_f32_16x16x32_f16(Al0, Bh0, accc[0][0], 0, 0, 0);
        accc[0][1] = __builtin_amdgcn_mfma_f32_16x16x32_f16(Al0, Bh1, accc[0][1], 0, 0, 0);
        accc[1][0] = __builtin_amdgcn_mfma_f32_16x16x32_f16(Al1, Bh0, accc[1][0], 0, 0, 0);
        accc[1][1] = __builtin_amdgcn_mfma_f32_16x16x32_f16(Al1, Bh1, accc[1][1], 0, 0, 0);
        accc[0][0] = __builtin_amdgcn_mfma_f32_16x16x32_f16(Ah0, Bl0, accc[0][0], 0, 0, 0);
        accc[0][1] = __builtin_amdgcn_mfma_f32_16x16x32_f16(Ah0, Bl1, accc[0][1], 0, 0, 0);
        accc[1][0] = __builtin_amdgcn_mfma_f32_16x16x32_f16(Ah1, Bl0, accc[1][0], 0, 0, 0);
        accc[1][1] = __builtin_amdgcn_mfma_f32_16x16x32_f16(Ah1, Bl1, accc[1][1], 0, 0, 0);
    };

    // ---- prologue: iterations 0 and 1 in flight (12 loads) ----
    stage(0);
    stage(1);

    // ---- main loop: one vmcnt+barrier per K=64; stage AFTER barrier (dist-2 safe) ----
    int rbase = 0;
    for (int t = 0; t < NIT; ++t) {
        if (t < NIT - 1) {
            asm volatile("s_waitcnt vmcnt(6)" ::: "memory");   // t's 6 landed; t+1's in flight
        } else {
            asm volatile("s_waitcnt vmcnt(0)" ::: "memory");
        }
        __builtin_amdgcn_s_barrier();
        if (t < NIT - 2) stage(t + 2);   // overwrites buffer consumed at iter t-1 (barrier-ordered)
        __builtin_amdgcn_sched_barrier(0);
        computeStep(rbase, 0);
        computeStep(rbase, 1);
        rbase += BUFSZ; if (rbase == NBUF * BUFSZ) rbase = 0;
    }

    __builtin_amdgcn_s_barrier();

    // ---- epilogue: logits -> LDS [64][132] f32 ----
    float* L = reinterpret_cast<float*>(smem);
    #pragma unroll
    for (int rf = 0; rf < 2; ++rf)
        #pragma unroll
        for (int cf = 0; cf < 2; ++cf) {
            const int col = cg * 32 + cf * 16 + idx;
            #pragma unroll
            for (int q = 0; q < 4; ++q) {
                const int lrow = rg * 32 + rf * 16 + g * 4 + q;
                L[lrow * LSTR + col] = accm[rf][cf][q] + accc[rf][cf][q] * 4.8828125e-4f;
            }
        }
    __syncthreads();

    // ---- fused softplus/noise/top-2/softmax: 8 threads per row, 64 rows ----
    {
        const int row = tid >> 3;
        const int j   = tid & 7;
        const int e0  = j * 8;
        const int grow = row_base + row;

        const float4 c0 = *reinterpret_cast<const float4*>(&L[row * LSTR + e0]);
        const float4 c1 = *reinterpret_cast<const float4*>(&L[row * LSTR + e0 + 4]);
        const float4 s0 = *reinterpret_cast<const float4*>(&L[row * LSTR + 64 + e0]);
        const float4 s1 = *reinterpret_cast<const float4*>(&L[row * LSTR + 64 + e0 + 4]);
        *reinterpret_cast<float4*>(&out[CLEAN_OFF + (size_t)grow * EDIM + e0])     = c0;
        *reinterpret_cast<float4*>(&out[CLEAN_OFF + (size_t)grow * EDIM + e0 + 4]) = c1;

        const float4 z0 = *reinterpret_cast<const float4*>(&noise[(size_t)grow * EDIM + e0]);
        const float4 z1 = *reinterpret_cast<const float4*>(&noise[(size_t)grow * EDIM + e0 + 4]);

        float nv[8];
        nv[0] = fmaf(softplus_f(s0.x), z0.x, c0.x);
        nv[1] = fmaf(softplus_f(s0.y), z0.y, c0.y);
        nv[2] = fmaf(softplus_f(s0.z), z0.z, c0.z);
        nv[3] = fmaf(softplus_f(s0.w), z0.w, c0.w);
        nv[4] = fmaf(softplus_f(s1.x), z1.x, c1.x);
        nv[5] = fmaf(softplus_f(s1.y), z1.y, c1.y);
        nv[6] = fmaf(softplus_f(s1.z), z1.z, c1.z);
        nv[7] = fmaf(softplus_f(s1.w), z1.w, c1.w);

        float v0 = nv[0], v1 = -INFINITY;
        int   i0 = e0,    i1 = -1;
        #pragma unroll
        for (int m = 1; m < 8; ++m) {
            const float v = nv[m]; const int e = e0 + m;
            if (v > v0)      { v1 = v0; i1 = i0; v0 = v; i0 = e; }
            else if (v > v1) { v1 = v;  i1 = e; }
        }
        #pragma unroll
        for (int d = 1; d < 8; d <<= 1) {
            const float ov0 = __shfl_xor(v0, d); const int oi0 = __shfl_xor(i0, d);
            const float ov1 = __shfl_xor(v1, d); const int oi1 = __shfl_xor(i1, d);
            const bool aFirst = (v0 > ov0) || (v0 == ov0 && i0 < oi0);
            float n0, n1; int ni0, ni1;
            if (aFirst) {
                n0 = v0; ni0 = i0;
                const bool s = (v1 > ov0) || (v1 == ov0 && i1 < oi0);
                n1 = s ? v1 : ov0; ni1 = s ? i1 : oi0;
            } else {
                n0 = ov0; ni0 = oi0;
                const bool s = (ov1 > v0) || (ov1 == v0 && oi1 < i0);
                n1 = s ? ov1 : v0; ni1 = s ? oi1 : i0;
            }
            v0 = n0; i0 = ni0; v1 = n1; i1 = ni1;
        }
        if (j == 0) {
            const float ex = expf(v1 - v0);
            const float w0 = 1.0f / (1.0f + ex);
            const float w1 = 1.0f - w0;
            out[(size_t)grow * 2 + 0] = w0;
            out[(size_t)grow * 2 + 1] = w1;
            out[IDX_OFF + (size_t)grow * 2 + 0] = (float)i0;
            out[IDX_OFF + (size_t)grow * 2 + 1] = (float)i1;
        }
    }
}

extern "C" void kernel_launch(void* const* d_in, const int* in_sizes, int n_in,
                              void* d_out, int out_size, void* d_ws, size_t ws_size,
                              hipStream_t stream) {
    const float* x     = (const float*)d_in[0];
    const float* Wg    = (const float*)d_in[1];
    const float* Wn    = (const float*)d_in[2];
    const float* noise = (const float*)d_in[3];
    float* out = (float*)d_out;

    _Float16* wh = (_Float16*)d_ws;
    _Float16* wl = wh + WPACK;               // packed matrix is 262144 f16 (512KB)

    split_w_kernel<<<dim3(128), dim3(256), 0, stream>>>(Wg, Wn, wh, wl);
    gating_mfma_kernel<<<dim3(NROWS / BM), dim3(512), NBUF * BUFSZ, stream>>>(x, noise, wh, wl, out);
}

// Round 10
// 65.038 us; speedup vs baseline: 1.0447x; 1.0447x over previous
//
#include <hip/hip_runtime.h>
#include <math.h>

// NoisyTopKGating via fp16x2-split MFMA. Round-8 pipeline (K=32/iter, counted vmcnt)
// with BM=32 / 256 threads / 512 blocks -> 2 resident blocks per CU (TLP attacks
// the barrier-lockstep stall). NBUF=3 x 20KB buffers (60KB dynamic LDS), stage
// issued AFTER the barrier (race-free at prefetch distance 2 with 3 buffers).
// out layout (f32 flat): weights [N,2] @0, indices-as-float [N,2] @32768, clean [N,64] @65536.
// d_ws: Bh packed frags (512KB) @0, Bl packed frags (512KB) @+262144 f16.
// Packed layout (f16 units): [(kc*8 + cg*2 + cf)*512 + lane*8 + j]
//   col = cg*32 + cf*16 + (lane&15),  k = kc*32 + (lane>>4)*8 + j.

constexpr int NROWS = 16384;
constexpr int DDIM  = 2048;
constexpr int EDIM  = 64;
constexpr int BM    = 32;             // rows per block
constexpr int NKS   = 64;             // k-steps of 32
constexpr int LSTR  = 132;            // epilogue LDS stride (floats)
constexpr int IDX_OFF   = NROWS * 2;
constexpr int CLEAN_OFF = NROWS * 4;
constexpr size_t WPACK = 262144;      // f16 elements per packed matrix (128*2048)
// buffer: X [32 rows][128B] 4KB @0, Bh 8KB @4096, Bl 8KB @12288
constexpr int BUFSZ = 20480;
constexpr int NBUF  = 3;              // 60KB dynamic LDS -> 2 blocks/CU

typedef _Float16 f16x8 __attribute__((ext_vector_type(8)));
typedef float    f32x4 __attribute__((ext_vector_type(4)));

__device__ __forceinline__ float softplus_f(float z) {
    return fmaxf(z, 0.0f) + log1pf(expf(-fabsf(z)));
}

__device__ __forceinline__ void gload16(const void* g, void* l) {
    __builtin_amdgcn_global_load_lds(
        (const __attribute__((address_space(1))) unsigned int*)g,
        (__attribute__((address_space(3))) unsigned int*)l, 16, 0, 0);
}

// ---------- pre-kernel: split + pack weights into frag-ordered hi/lo ----------
__global__ __launch_bounds__(256) void split_w_kernel(
    const float* __restrict__ Wg, const float* __restrict__ Wn,
    _Float16* __restrict__ wh, _Float16* __restrict__ wl)
{
    const int t    = blockIdx.x * 256 + threadIdx.x;   // 0..32767
    const int grp  = t >> 6;                           // kc*8 + cg*2 + cf  (0..511)
    const int lane = t & 63;
    const int kc   = grp >> 3;
    const int cg   = (grp >> 1) & 3;
    const int cf   = grp & 1;
    const int col  = cg * 32 + cf * 16 + (lane & 15);
    const int k0   = kc * 32 + (lane >> 4) * 8;
    const float* src = (col < 64) ? &Wg[(size_t)col * DDIM + k0]
                                  : &Wn[(size_t)(col - 64) * DDIM + k0];
    const float4 v0 = *reinterpret_cast<const float4*>(src);
    const float4 v1 = *reinterpret_cast<const float4*>(src + 4);
    float vv[8] = {v0.x, v0.y, v0.z, v0.w, v1.x, v1.y, v1.z, v1.w};
    union { _Float16 h[8]; uint4 u; } hh, ll;
    #pragma unroll
    for (int j = 0; j < 8; ++j) {
        hh.h[j] = (_Float16)vv[j];
        ll.h[j] = (_Float16)((vv[j] - (float)hh.h[j]) * 2048.0f);
    }
    const size_t off = (size_t)grp * 512 + lane * 8;
    *reinterpret_cast<uint4*>(&wh[off]) = hh.u;
    *reinterpret_cast<uint4*>(&wl[off]) = ll.u;
}

__device__ __forceinline__ void split8(const float4 a, const float4 b, f16x8& h, f16x8& l) {
    const float v[8] = {a.x, a.y, a.z, a.w, b.x, b.y, b.z, b.w};
    #pragma unroll
    for (int j = 0; j < 8; ++j) {
        const _Float16 hh = (_Float16)v[j];
        h[j] = hh;
        l[j] = (_Float16)((v[j] - (float)hh) * 2048.0f);
    }
}

// ---------- main fused kernel ----------
__global__ __launch_bounds__(256, 2) void gating_mfma_kernel(
    const float* __restrict__ x,
    const float* __restrict__ noise,
    const _Float16* __restrict__ whp,
    const _Float16* __restrict__ wlp,
    float* __restrict__ out)
{
    extern __shared__ __align__(16) unsigned char smem[];   // NBUF*BUFSZ = 60KB

    const int tid = threadIdx.x;
    const int row_base = blockIdx.x * BM;
    const int lane = tid & 63;
    const int cg   = tid >> 6;           // col-group 0..3 (4 waves)
    const int g    = (lane >> 4) & 3;    // k-group
    const int idx  = lane & 15;

    // ---- staging addresses ----
    // x: thread stages 16B of [32 rows][128B]; LDS dest linear tid*16; source pre-swizzled
    const int sr  = tid >> 3;            // row 0..31
    const int sq  = tid & 7;             // 16B slot 0..7
    const int sq2 = sq ^ (sr & 7);
    const float* xsrc = x + (size_t)(row_base + sr) * DDIM + sq2 * 4;
    const char* bhsrc = (const char*)whp + tid * 16;
    const char* blsrc = (const char*)wlp + tid * 16;

    // ---- A-frag read offsets (swizzled): row = rf*16 + idx, slots (2g+j)^(row&7) ----
    int aoff[2][2];
    #pragma unroll
    for (int rf = 0; rf < 2; ++rf) {
        const int row = rf * 16 + idx;
        #pragma unroll
        for (int j = 0; j < 2; ++j)
            aoff[rf][j] = row * 128 + (((g * 2 + j) ^ (row & 7)) << 4);
    }
    // ---- B-frag read offsets ----
    int bhoff[2], bloff[2];
    #pragma unroll
    for (int cf = 0; cf < 2; ++cf) {
        bhoff[cf] = 4096  + (cg * 2 + cf) * 1024 + lane * 16;
        bloff[cf] = 12288 + (cg * 2 + cf) * 1024 + lane * 16;
    }

    f32x4 accm[2][2], accc[2][2];
    #pragma unroll
    for (int rf = 0; rf < 2; ++rf)
        #pragma unroll
        for (int cf = 0; cf < 2; ++cf) { accm[rf][cf] = (f32x4)0.0f; accc[rf][cf] = (f32x4)0.0f; }

    auto stage = [&](int u, int b) {     // u = k-step index; 5 loads
        gload16(xsrc + u * 32,                        smem + b + tid * 16);
        gload16(bhsrc + (size_t)u * 8192,             smem + b + 4096  + tid * 16);
        gload16(bhsrc + (size_t)u * 8192 + 4096,      smem + b + 8192  + tid * 16);
        gload16(blsrc + (size_t)u * 8192,             smem + b + 12288 + tid * 16);
        gload16(blsrc + (size_t)u * 8192 + 4096,      smem + b + 16384 + tid * 16);
    };

    auto computeStep = [&](int b) {
        const float4 a00 = *reinterpret_cast<const float4*>(&smem[b + aoff[0][0]]);
        const float4 a01 = *reinterpret_cast<const float4*>(&smem[b + aoff[0][1]]);
        const float4 a10 = *reinterpret_cast<const float4*>(&smem[b + aoff[1][0]]);
        const float4 a11 = *reinterpret_cast<const float4*>(&smem[b + aoff[1][1]]);
        const f16x8 Bh0 = *reinterpret_cast<const f16x8*>(&smem[b + bhoff[0]]);
        const f16x8 Bh1 = *reinterpret_cast<const f16x8*>(&smem[b + bhoff[1]]);
        const f16x8 Bl0 = *reinterpret_cast<const f16x8*>(&smem[b + bloff[0]]);
        const f16x8 Bl1 = *reinterpret_cast<const f16x8*>(&smem[b + bloff[1]]);

        f16x8 Ah0, Al0, Ah1, Al1;
        split8(a00, a01, Ah0, Al0);
        split8(a10, a11, Ah1, Al1);

        accm[0][0] = __builtin_amdgcn_mfma_f32_16x16x32_f16(Ah0, Bh0, accm[0][0], 0, 0, 0);
        accm[0][1] = __builtin_amdgcn_mfma_f32_16x16x32_f16(Ah0, Bh1, accm[0][1], 0, 0, 0);
        accm[1][0] = __builtin_amdgcn_mfma_f32_16x16x32_f16(Ah1, Bh0, accm[1][0], 0, 0, 0);
        accm[1][1] = __builtin_amdgcn_mfma_f32_16x16x32_f16(Ah1, Bh1, accm[1][1], 0, 0, 0);
        accc[0][0] = __builtin_amdgcn_mfma_f32_16x16x32_f16(Al0, Bh0, accc[0][0], 0, 0, 0);
        accc[0][1] = __builtin_amdgcn_mfma_f32_16x16x32_f16(Al0, Bh1, accc[0][1], 0, 0, 0);
        accc[1][0] = __builtin_amdgcn_mfma_f32_16x16x32_f16(Al1, Bh0, accc[1][0], 0, 0, 0);
        accc[1][1] = __builtin_amdgcn_mfma_f32_16x16x32_f16(Al1, Bh1, accc[1][1], 0, 0, 0);
        accc[0][0] = __builtin_amdgcn_mfma_f32_16x16x32_f16(Ah0, Bl0, accc[0][0], 0, 0, 0);
        accc[0][1] = __builtin_amdgcn_mfma_f32_16x16x32_f16(Ah0, Bl1, accc[0][1], 0, 0, 0);
        accc[1][0] = __builtin_amdgcn_mfma_f32_16x16x32_f16(Ah1, Bl0, accc[1][0], 0, 0, 0);
        accc[1][1] = __builtin_amdgcn_mfma_f32_16x16x32_f16(Ah1, Bl1, accc[1][1], 0, 0, 0);
    };

    // ---- prologue: k-steps 0 and 1 in flight (10 loads) ----
    stage(0, 0);
    stage(1, BUFSZ);

    // ---- main loop: vmcnt(5) counted; stage AFTER barrier (NBUF=3 race-free) ----
    int rbase = 0, wbase = 2 * BUFSZ;
    for (int t = 0; t < NKS; ++t) {
        if (t < NKS - 1) {
            asm volatile("s_waitcnt vmcnt(5)" ::: "memory");   // t's 5 landed; t+1's in flight
        } else {
            asm volatile("s_waitcnt vmcnt(0)" ::: "memory");
        }
        __builtin_amdgcn_s_barrier();
        if (t < NKS - 2) stage(t + 2, wbase);   // overwrites buffer consumed at t-1 (barrier-ordered)
        __builtin_amdgcn_sched_barrier(0);
        computeStep(rbase);
        rbase += BUFSZ; if (rbase == NBUF * BUFSZ) rbase = 0;
        wbase += BUFSZ; if (wbase == NBUF * BUFSZ) wbase = 0;
    }

    __builtin_amdgcn_s_barrier();

    // ---- epilogue: logits -> LDS [32][132] f32 ----
    float* L = reinterpret_cast<float*>(smem);
    #pragma unroll
    for (int rf = 0; rf < 2; ++rf)
        #pragma unroll
        for (int cf = 0; cf < 2; ++cf) {
            const int col = cg * 32 + cf * 16 + idx;
            #pragma unroll
            for (int q = 0; q < 4; ++q) {
                const int lrow = rf * 16 + g * 4 + q;
                L[lrow * LSTR + col] = accm[rf][cf][q] + accc[rf][cf][q] * 4.8828125e-4f;
            }
        }
    __syncthreads();

    // ---- fused softplus/noise/top-2/softmax: 8 threads per row, 32 rows ----
    {
        const int row = tid >> 3;
        const int j   = tid & 7;
        const int e0  = j * 8;
        const int grow = row_base + row;

        const float4 c0 = *reinterpret_cast<const float4*>(&L[row * LSTR + e0]);
        const float4 c1 = *reinterpret_cast<const float4*>(&L[row * LSTR + e0 + 4]);
        const float4 s0 = *reinterpret_cast<const float4*>(&L[row * LSTR + 64 + e0]);
        const float4 s1 = *reinterpret_cast<const float4*>(&L[row * LSTR + 64 + e0 + 4]);
        *reinterpret_cast<float4*>(&out[CLEAN_OFF + (size_t)grow * EDIM + e0])     = c0;
        *reinterpret_cast<float4*>(&out[CLEAN_OFF + (size_t)grow * EDIM + e0 + 4]) = c1;

        const float4 z0 = *reinterpret_cast<const float4*>(&noise[(size_t)grow * EDIM + e0]);
        const float4 z1 = *reinterpret_cast<const float4*>(&noise[(size_t)grow * EDIM + e0 + 4]);

        float nv[8];
        nv[0] = fmaf(softplus_f(s0.x), z0.x, c0.x);
        nv[1] = fmaf(softplus_f(s0.y), z0.y, c0.y);
        nv[2] = fmaf(softplus_f(s0.z), z0.z, c0.z);
        nv[3] = fmaf(softplus_f(s0.w), z0.w, c0.w);
        nv[4] = fmaf(softplus_f(s1.x), z1.x, c1.x);
        nv[5] = fmaf(softplus_f(s1.y), z1.y, c1.y);
        nv[6] = fmaf(softplus_f(s1.z), z1.z, c1.z);
        nv[7] = fmaf(softplus_f(s1.w), z1.w, c1.w);

        float v0 = nv[0], v1 = -INFINITY;
        int   i0 = e0,    i1 = -1;
        #pragma unroll
        for (int m = 1; m < 8; ++m) {
            const float v = nv[m]; const int e = e0 + m;
            if (v > v0)      { v1 = v0; i1 = i0; v0 = v; i0 = e; }
            else if (v > v1) { v1 = v;  i1 = e; }
        }
        #pragma unroll
        for (int d = 1; d < 8; d <<= 1) {
            const float ov0 = __shfl_xor(v0, d); const int oi0 = __shfl_xor(i0, d);
            const float ov1 = __shfl_xor(v1, d); const int oi1 = __shfl_xor(i1, d);
            const bool aFirst = (v0 > ov0) || (v0 == ov0 && i0 < oi0);
            float n0, n1; int ni0, ni1;
            if (aFirst) {
                n0 = v0; ni0 = i0;
                const bool s = (v1 > ov0) || (v1 == ov0 && i1 < oi0);
                n1 = s ? v1 : ov0; ni1 = s ? i1 : oi0;
            } else {
                n0 = ov0; ni0 = oi0;
                const bool s = (ov1 > v0) || (ov1 == v0 && oi1 < i0);
                n1 = s ? ov1 : v0; ni1 = s ? oi1 : i0;
            }
            v0 = n0; i0 = ni0; v1 = n1; i1 = ni1;
        }
        if (j == 0) {
            const float ex = expf(v1 - v0);
            const float w0 = 1.0f / (1.0f + ex);
            const float w1 = 1.0f - w0;
            out[(size_t)grow * 2 + 0] = w0;
            out[(size_t)grow * 2 + 1] = w1;
            out[IDX_OFF + (size_t)grow * 2 + 0] = (float)i0;
            out[IDX_OFF + (size_t)grow * 2 + 1] = (float)i1;
        }
    }
}

extern "C" void kernel_launch(void* const* d_in, const int* in_sizes, int n_in,
                              void* d_out, int out_size, void* d_ws, size_t ws_size,
                              hipStream_t stream) {
    const float* x     = (const float*)d_in[0];
    const float* Wg    = (const float*)d_in[1];
    const float* Wn    = (const float*)d_in[2];
    const float* noise = (const float*)d_in[3];
    float* out = (float*)d_out;

    _Float16* wh = (_Float16*)d_ws;
    _Float16* wl = wh + WPACK;               // packed matrix is 262144 f16 (512KB)

    split_w_kernel<<<dim3(128), dim3(256), 0, stream>>>(Wg, Wn, wh, wl);
    gating_mfma_kernel<<<dim3(NROWS / BM), dim3(256), NBUF * BUFSZ, stream>>>(x, noise, wh, wl, out);
}

// Round 12
// 55.605 us; speedup vs baseline: 1.2219x; 1.1696x over previous
//
#include <hip/hip_runtime.h>
#include <math.h>

// NoisyTopKGating via fp16x2-split MFMA.
// x staged via global_load_lds + counted vmcnt (proven R8 discipline, NBUF=4, dist-2).
// B loaded to a 2-slot REGISTER pipeline with plain C++ loads (compiler-managed
// waitcnt — no inline-asm loads), pinned at distance 2 by sched_barrier(0) fences.
// BM=32, 256 threads (4 waves = 4 col-groups), 512 blocks -> 2 independent
// barrier domains per CU (TLP covers the per-body barrier stall).
// out layout (f32 flat): weights [N,2] @0, indices-as-float [N,2] @32768, clean [N,64] @65536.
// d_ws: Bh packed frags (512KB) @0, Bl packed frags (512KB) @+262144 f16.
// Packed layout (f16 units): [(kc*8 + cg*2 + cf)*512 + lane*8 + j]
//   col = cg*32 + cf*16 + (lane&15),  k = kc*32 + (lane>>4)*8 + j.

constexpr int NROWS = 16384;
constexpr int DDIM  = 2048;
constexpr int EDIM  = 64;
constexpr int BM    = 32;             // rows per block
constexpr int NKS   = 64;             // k-steps of 32
constexpr int LSTR  = 132;            // epilogue LDS stride (floats)
constexpr int IDX_OFF   = NROWS * 2;
constexpr int CLEAN_OFF = NROWS * 4;
constexpr size_t WPACK = 262144;      // f16 elements per packed matrix (128*2048)
constexpr int XBUF  = 4096;           // x buffer: [32 rows][128B]
constexpr int NBUF  = 4;              // 16KB x staging
constexpr int LDSSZ = 17408;          // max(16KB staging, 16.9KB epilogue)

typedef _Float16 f16x8 __attribute__((ext_vector_type(8)));
typedef float    f32x4 __attribute__((ext_vector_type(4)));

__device__ __forceinline__ float softplus_f(float z) {
    return fmaxf(z, 0.0f) + log1pf(expf(-fabsf(z)));
}

__device__ __forceinline__ void gload16(const void* g, void* l) {
    __builtin_amdgcn_global_load_lds(
        (const __attribute__((address_space(1))) unsigned int*)g,
        (__attribute__((address_space(3))) unsigned int*)l, 16, 0, 0);
}

// ---------- pre-kernel: split + pack weights into frag-ordered hi/lo ----------
__global__ __launch_bounds__(256) void split_w_kernel(
    const float* __restrict__ Wg, const float* __restrict__ Wn,
    _Float16* __restrict__ wh, _Float16* __restrict__ wl)
{
    const int t    = blockIdx.x * 256 + threadIdx.x;   // 0..32767
    const int grp  = t >> 6;                           // kc*8 + cg*2 + cf  (0..511)
    const int lane = t & 63;
    const int kc   = grp >> 3;
    const int cg   = (grp >> 1) & 3;
    const int cf   = grp & 1;
    const int col  = cg * 32 + cf * 16 + (lane & 15);
    const int k0   = kc * 32 + (lane >> 4) * 8;
    const float* src = (col < 64) ? &Wg[(size_t)col * DDIM + k0]
                                  : &Wn[(size_t)(col - 64) * DDIM + k0];
    const float4 v0 = *reinterpret_cast<const float4*>(src);
    const float4 v1 = *reinterpret_cast<const float4*>(src + 4);
    float vv[8] = {v0.x, v0.y, v0.z, v0.w, v1.x, v1.y, v1.z, v1.w};
    union { _Float16 h[8]; uint4 u; } hh, ll;
    #pragma unroll
    for (int j = 0; j < 8; ++j) {
        hh.h[j] = (_Float16)vv[j];
        ll.h[j] = (_Float16)((vv[j] - (float)hh.h[j]) * 2048.0f);
    }
    const size_t off = (size_t)grp * 512 + lane * 8;
    *reinterpret_cast<uint4*>(&wh[off]) = hh.u;
    *reinterpret_cast<uint4*>(&wl[off]) = ll.u;
}

__device__ __forceinline__ void split8(const float4 a, const float4 b, f16x8& h, f16x8& l) {
    const float v[8] = {a.x, a.y, a.z, a.w, b.x, b.y, b.z, b.w};
    #pragma unroll
    for (int j = 0; j < 8; ++j) {
        const _Float16 hh = (_Float16)v[j];
        h[j] = hh;
        l[j] = (_Float16)((v[j] - (float)hh) * 2048.0f);
    }
}

// ---------- main fused kernel ----------
__global__ __launch_bounds__(256, 2) void gating_mfma_kernel(
    const float* __restrict__ x,
    const float* __restrict__ noise,
    const _Float16* __restrict__ whp,
    const _Float16* __restrict__ wlp,
    float* __restrict__ out)
{
    extern __shared__ __align__(16) unsigned char smem[];   // LDSSZ bytes

    const int tid = threadIdx.x;
    const int row_base = blockIdx.x * BM;
    const int lane = tid & 63;
    const int cg   = tid >> 6;           // col-group 0..3 (4 waves)
    const int g    = (lane >> 4) & 3;    // k-group
    const int idx  = lane & 15;

    // ---- x staging: thread stages 16B of [32 rows][128B]; source pre-swizzled ----
    const int sr  = tid >> 3;            // row 0..31
    const int sq  = tid & 7;             // 16B slot
    const int sq2 = sq ^ (sr & 7);
    const float* xsrc = x + (size_t)(row_base + sr) * DDIM + sq2 * 4;

    // ---- B base pointers (fragment-packed; per-wave 1KB contiguous per load) ----
    const _Float16* bh = whp + (size_t)cg * 1024 + lane * 8;
    const _Float16* bl = wlp + (size_t)cg * 1024 + lane * 8;

    // ---- A-frag read offsets (swizzled): row = rf*16 + idx, slots (2g+j)^(row&7) ----
    int aoff[2][2];
    #pragma unroll
    for (int rf = 0; rf < 2; ++rf) {
        const int row = rf * 16 + idx;
        #pragma unroll
        for (int j = 0; j < 2; ++j)
            aoff[rf][j] = row * 128 + (((g * 2 + j) ^ (row & 7)) << 4);
    }

    f32x4 accm[2][2], accc[2][2];
    #pragma unroll
    for (int rf = 0; rf < 2; ++rf)
        #pragma unroll
        for (int cf = 0; cf < 2; ++cf) { accm[rf][cf] = (f32x4)0.0f; accc[rf][cf] = (f32x4)0.0f; }

    auto stageX = [&](int u) {
        gload16(xsrc + u * 32, smem + (u & (NBUF - 1)) * XBUF + tid * 16);
    };
    auto loadW = [&](int u, float4& h0, float4& h1, float4& l0, float4& l1) {
        const _Float16* ph = bh + (size_t)u * 4096;
        const _Float16* pl = bl + (size_t)u * 4096;
        h0 = *reinterpret_cast<const float4*>(ph);
        h1 = *reinterpret_cast<const float4*>(ph + 512);
        l0 = *reinterpret_cast<const float4*>(pl);
        l1 = *reinterpret_cast<const float4*>(pl + 512);
    };

    auto compute = [&](int t, const float4& h0, const float4& h1,
                       const float4& l0, const float4& l1) {
        const int b = (t & (NBUF - 1)) * XBUF;
        const float4 a00 = *reinterpret_cast<const float4*>(&smem[b + aoff[0][0]]);
        const float4 a01 = *reinterpret_cast<const float4*>(&smem[b + aoff[0][1]]);
        const float4 a10 = *reinterpret_cast<const float4*>(&smem[b + aoff[1][0]]);
        const float4 a11 = *reinterpret_cast<const float4*>(&smem[b + aoff[1][1]]);
        const f16x8 Bh0 = __builtin_bit_cast(f16x8, h0);
        const f16x8 Bh1 = __builtin_bit_cast(f16x8, h1);
        const f16x8 Bl0 = __builtin_bit_cast(f16x8, l0);
        const f16x8 Bl1 = __builtin_bit_cast(f16x8, l1);

        f16x8 Ah0, Al0, Ah1, Al1;
        split8(a00, a01, Ah0, Al0);
        split8(a10, a11, Ah1, Al1);

        accm[0][0] = __builtin_amdgcn_mfma_f32_16x16x32_f16(Ah0, Bh0, accm[0][0], 0, 0, 0);
        accm[0][1] = __builtin_amdgcn_mfma_f32_16x16x32_f16(Ah0, Bh1, accm[0][1], 0, 0, 0);
        accm[1][0] = __builtin_amdgcn_mfma_f32_16x16x32_f16(Ah1, Bh0, accm[1][0], 0, 0, 0);
        accm[1][1] = __builtin_amdgcn_mfma_f32_16x16x32_f16(Ah1, Bh1, accm[1][1], 0, 0, 0);
        accc[0][0] = __builtin_amdgcn_mfma_f32_16x16x32_f16(Al0, Bh0, accc[0][0], 0, 0, 0);
        accc[0][1] = __builtin_amdgcn_mfma_f32_16x16x32_f16(Al0, Bh1, accc[0][1], 0, 0, 0);
        accc[1][0] = __builtin_amdgcn_mfma_f32_16x16x32_f16(Al1, Bh0, accc[1][0], 0, 0, 0);
        accc[1][1] = __builtin_amdgcn_mfma_f32_16x16x32_f16(Al1, Bh1, accc[1][1], 0, 0, 0);
        accc[0][0] = __builtin_amdgcn_mfma_f32_16x16x32_f16(Ah0, Bl0, accc[0][0], 0, 0, 0);
        accc[0][1] = __builtin_amdgcn_mfma_f32_16x16x32_f16(Ah0, Bl1, accc[0][1], 0, 0, 0);
        accc[1][0] = __builtin_amdgcn_mfma_f32_16x16x32_f16(Ah1, Bl0, accc[1][0], 0, 0, 0);
        accc[1][1] = __builtin_amdgcn_mfma_f32_16x16x32_f16(Ah1, Bl1, accc[1][1], 0, 0, 0);
    };

    // ---- B register slots (parity rotation; loaded at distance 2) ----
    float4 s0h0, s0h1, s0l0, s0l1, s1h0, s1h1, s1l0, s1l1;

    // ---- prologue: x0,W0,x1,W1 (issue order matches steady-state counting) ----
    stageX(0); loadW(0, s0h0, s0h1, s0l0, s0l1);
    stageX(1); loadW(1, s1h0, s1h1, s1l0, s1l1);
    __builtin_amdgcn_sched_barrier(0);

    // ---- main loop: t = 0..61 in parity pairs ----
    // Body: stageX(t+2) | vmcnt(6) drains {x(t),W(t)} | barrier | compute(t) | loadW(t+2)
    for (int tt = 0; tt < 31; ++tt) {
        const int t0 = 2 * tt;
        // even k-step: slot 0
        stageX(t0 + 2);
        asm volatile("s_waitcnt vmcnt(6)" ::: "memory");
        __builtin_amdgcn_s_barrier();
        __builtin_amdgcn_sched_barrier(0);
        compute(t0, s0h0, s0h1, s0l0, s0l1);
        loadW(t0 + 2, s0h0, s0h1, s0l0, s0l1);
        __builtin_amdgcn_sched_barrier(0);
        // odd k-step: slot 1
        stageX(t0 + 3);
        asm volatile("s_waitcnt vmcnt(6)" ::: "memory");
        __builtin_amdgcn_s_barrier();
        __builtin_amdgcn_sched_barrier(0);
        compute(t0 + 1, s1h0, s1h1, s1l0, s1l1);
        loadW(t0 + 3, s1h0, s1h1, s1l0, s1l1);
        __builtin_amdgcn_sched_barrier(0);
    }
    // ---- tail t=62 (slot 0): newer in flight = stageX(63)+loadW(63) = 5 ----
    asm volatile("s_waitcnt vmcnt(5)" ::: "memory");
    __builtin_amdgcn_s_barrier();
    __builtin_amdgcn_sched_barrier(0);
    compute(62, s0h0, s0h1, s0l0, s0l1);
    // ---- tail t=63 (slot 1) ----
    asm volatile("s_waitcnt vmcnt(0)" ::: "memory");
    __builtin_amdgcn_s_barrier();
    __builtin_amdgcn_sched_barrier(0);
    compute(63, s1h0, s1h1, s1l0, s1l1);

    __builtin_amdgcn_s_barrier();

    // ---- epilogue: logits -> LDS [32][132] f32 ----
    float* L = reinterpret_cast<float*>(smem);
    #pragma unroll
    for (int rf = 0; rf < 2; ++rf)
        #pragma unroll
        for (int cf = 0; cf < 2; ++cf) {
            const int col = cg * 32 + cf * 16 + idx;
            #pragma unroll
            for (int q = 0; q < 4; ++q) {
                const int lrow = rf * 16 + g * 4 + q;
                L[lrow * LSTR + col] = accm[rf][cf][q] + accc[rf][cf][q] * 4.8828125e-4f;
            }
        }
    __syncthreads();

    // ---- fused softplus/noise/top-2/softmax: 8 threads per row, 32 rows ----
    {
        const int row = tid >> 3;
        const int j   = tid & 7;
        const int e0  = j * 8;
        const int grow = row_base + row;

        const float4 c0 = *reinterpret_cast<const float4*>(&L[row * LSTR + e0]);
        const float4 c1 = *reinterpret_cast<const float4*>(&L[row * LSTR + e0 + 4]);
        const float4 s0 = *reinterpret_cast<const float4*>(&L[row * LSTR + 64 + e0]);
        const float4 s1 = *reinterpret_cast<const float4*>(&L[row * LSTR + 64 + e0 + 4]);
        *reinterpret_cast<float4*>(&out[CLEAN_OFF + (size_t)grow * EDIM + e0])     = c0;
        *reinterpret_cast<float4*>(&out[CLEAN_OFF + (size_t)grow * EDIM + e0 + 4]) = c1;

        const float4 z0 = *reinterpret_cast<const float4*>(&noise[(size_t)grow * EDIM + e0]);
        const float4 z1 = *reinterpret_cast<const float4*>(&noise[(size_t)grow * EDIM + e0 + 4]);

        float nv[8];
        nv[0] = fmaf(softplus_f(s0.x), z0.x, c0.x);
        nv[1] = fmaf(softplus_f(s0.y), z0.y, c0.y);
        nv[2] = fmaf(softplus_f(s0.z), z0.z, c0.z);
        nv[3] = fmaf(softplus_f(s0.w), z0.w, c0.w);
        nv[4] = fmaf(softplus_f(s1.x), z1.x, c1.x);
        nv[5] = fmaf(softplus_f(s1.y), z1.y, c1.y);
        nv[6] = fmaf(softplus_f(s1.z), z1.z, c1.z);
        nv[7] = fmaf(softplus_f(s1.w), z1.w, c1.w);

        float v0 = nv[0], v1 = -INFINITY;
        int   i0 = e0,    i1 = -1;
        #pragma unroll
        for (int m = 1; m < 8; ++m) {
            const float v = nv[m]; const int e = e0 + m;
            if (v > v0)      { v1 = v0; i1 = i0; v0 = v; i0 = e; }
            else if (v > v1) { v1 = v;  i1 = e; }
        }
        #pragma unroll
        for (int d = 1; d < 8; d <<= 1) {
            const float ov0 = __shfl_xor(v0, d); const int oi0 = __shfl_xor(i0, d);
            const float ov1 = __shfl_xor(v1, d); const int oi1 = __shfl_xor(i1, d);
            const bool aFirst = (v0 > ov0) || (v0 == ov0 && i0 < oi0);
            float n0, n1; int ni0, ni1;
            if (aFirst) {
                n0 = v0; ni0 = i0;
                const bool s = (v1 > ov0) || (v1 == ov0 && i1 < oi0);
                n1 = s ? v1 : ov0; ni1 = s ? i1 : oi0;
            } else {
                n0 = ov0; ni0 = oi0;
                const bool s = (ov1 > v0) || (ov1 == v0 && oi1 < i0);
                n1 = s ? ov1 : v0; ni1 = s ? oi1 : i0;
            }
            v0 = n0; i0 = ni0; v1 = n1; i1 = ni1;
        }
        if (j == 0) {
            const float ex = expf(v1 - v0);
            const float w0 = 1.0f / (1.0f + ex);
            const float w1 = 1.0f - w0;
            out[(size_t)grow * 2 + 0] = w0;
            out[(size_t)grow * 2 + 1] = w1;
            out[IDX_OFF + (size_t)grow * 2 + 0] = (float)i0;
            out[IDX_OFF + (size_t)grow * 2 + 1] = (float)i1;
        }
    }
}

extern "C" void kernel_launch(void* const* d_in, const int* in_sizes, int n_in,
                              void* d_out, int out_size, void* d_ws, size_t ws_size,
                              hipStream_t stream) {
    const float* x     = (const float*)d_in[0];
    const float* Wg    = (const float*)d_in[1];
    const float* Wn    = (const float*)d_in[2];
    const float* noise = (const float*)d_in[3];
    float* out = (float*)d_out;

    _Float16* wh = (_Float16*)d_ws;
    _Float16* wl = wh + WPACK;               // packed matrix is 262144 f16 (512KB)

    split_w_kernel<<<dim3(128), dim3(256), 0, stream>>>(Wg, Wn, wh, wl);
    gating_mfma_kernel<<<dim3(NROWS / BM), dim3(256), LDSSZ, stream>>>(x, noise, wh, wl, out);
}

// Round 13
// 52.955 us; speedup vs baseline: 1.2831x; 1.0500x over previous
//
#include <hip/hip_runtime.h>
#include <math.h>

// NoisyTopKGating via fp16x2-split MFMA, BM=128 row-tiles with K-split=2.
// Kernel 1: split_w packs W into per-wave-contiguous MFMA frags (hi + scaled-lo f16).
// Kernel 2: gemm_part — grid 256 (2 K-halves x 128 row-tiles), 512 thr (8 waves =
//   2 rg x 4 cg), R8 pipeline: global_load_lds staging, NBUF=4, dist-2, counted vmcnt(8).
//   Writes f32 partial logits to d_ws.
// Kernel 3: reduce_topk — sums halves, softplus/noise/top-2/softmax, writes all outputs.
// out layout (f32 flat): weights [N,2] @0, indices-as-float [N,2] @32768, clean [N,64] @65536.
// d_ws: wh (512KB) @0, wl (512KB) @512KB, partials [2][16384][128] f32 (16MB) @1MB.

constexpr int NROWS = 16384;
constexpr int DDIM  = 2048;
constexpr int EDIM  = 64;
constexpr int IDX_OFF   = NROWS * 2;
constexpr int CLEAN_OFF = NROWS * 4;
constexpr size_t WPACK = 262144;      // f16 elements per packed matrix (128*2048)
constexpr int BMAIN = 128;            // rows per main block
constexpr int NKS2  = 32;             // k-steps (of 32) per block: K-half = 1024
constexpr int BUFSZ2 = 32768;         // x 16KB @0, Bh 8KB @16384, Bl 8KB @24576
constexpr int NBUF2  = 4;             // 128KB dynamic LDS

typedef _Float16 f16x8 __attribute__((ext_vector_type(8)));
typedef float    f32x4 __attribute__((ext_vector_type(4)));

__device__ __forceinline__ float softplus_f(float z) {
    return fmaxf(z, 0.0f) + log1pf(expf(-fabsf(z)));
}

__device__ __forceinline__ void gload16(const void* g, void* l) {
    __builtin_amdgcn_global_load_lds(
        (const __attribute__((address_space(1))) unsigned int*)g,
        (__attribute__((address_space(3))) unsigned int*)l, 16, 0, 0);
}

// ---------- kernel 1: split + pack weights into frag-ordered hi/lo ----------
__global__ __launch_bounds__(256) void split_w_kernel(
    const float* __restrict__ Wg, const float* __restrict__ Wn,
    _Float16* __restrict__ wh, _Float16* __restrict__ wl)
{
    const int t    = blockIdx.x * 256 + threadIdx.x;   // 0..32767
    const int grp  = t >> 6;                           // kc*8 + cg*2 + cf  (0..511)
    const int lane = t & 63;
    const int kc   = grp >> 3;
    const int cg   = (grp >> 1) & 3;
    const int cf   = grp & 1;
    const int col  = cg * 32 + cf * 16 + (lane & 15);
    const int k0   = kc * 32 + (lane >> 4) * 8;
    const float* src = (col < 64) ? &Wg[(size_t)col * DDIM + k0]
                                  : &Wn[(size_t)(col - 64) * DDIM + k0];
    const float4 v0 = *reinterpret_cast<const float4*>(src);
    const float4 v1 = *reinterpret_cast<const float4*>(src + 4);
    float vv[8] = {v0.x, v0.y, v0.z, v0.w, v1.x, v1.y, v1.z, v1.w};
    union { _Float16 h[8]; uint4 u; } hh, ll;
    #pragma unroll
    for (int j = 0; j < 8; ++j) {
        hh.h[j] = (_Float16)vv[j];
        ll.h[j] = (_Float16)((vv[j] - (float)hh.h[j]) * 2048.0f);
    }
    const size_t off = (size_t)grp * 512 + lane * 8;
    *reinterpret_cast<uint4*>(&wh[off]) = hh.u;
    *reinterpret_cast<uint4*>(&wl[off]) = ll.u;
}

__device__ __forceinline__ void split8(const float4 a, const float4 b, f16x8& h, f16x8& l) {
    const float v[8] = {a.x, a.y, a.z, a.w, b.x, b.y, b.z, b.w};
    #pragma unroll
    for (int j = 0; j < 8; ++j) {
        const _Float16 hh = (_Float16)v[j];
        h[j] = hh;
        l[j] = (_Float16)((v[j] - (float)hh) * 2048.0f);
    }
}

// ---------- kernel 2: partial GEMM (128 rows x 128 cols x K=1024 per block) ----------
__global__ __launch_bounds__(512, 1) void gemm_part_kernel(
    const float* __restrict__ x,
    const _Float16* __restrict__ whp,
    const _Float16* __restrict__ wlp,
    float* __restrict__ pbuf)
{
    extern __shared__ __align__(16) unsigned char smem[];   // NBUF2*BUFSZ2 = 128KB

    const int tid  = threadIdx.x;
    const int lane = tid & 63;
    const int wid  = tid >> 6;            // 0..7
    const int rg   = wid >> 2;            // row-group 0..1 (64 rows each)
    const int cg   = wid & 3;             // col-group 0..3 (32 cols each)
    const int g    = (lane >> 4) & 3;
    const int idx  = lane & 15;
    const int kh   = blockIdx.x >> 7;     // K-half 0..1
    const int rt   = blockIdx.x & 127;    // row-tile
    const int row_base = rt * BMAIN;

    // ---- staging addresses (thread stages 64B/iter: x lo, x hi, Bh, Bl) ----
    const int sr  = tid >> 3;             // 0..63
    const int sq  = tid & 7;
    const int sq2 = sq ^ (sr & 7);        // pre-swizzled source slot
    const float* xs0 = x + (size_t)(row_base + sr) * DDIM + kh * 1024 + sq2 * 4;
    const float* xs1 = xs0 + (size_t)64 * DDIM;
    const char* bhsrc = (const char*)whp + (size_t)kh * 524288 + tid * 16;  // 32 ksteps * 16KB... (bytes: kh*32*8192*2? no)
    const char* blsrc = (const char*)wlp + (size_t)kh * 524288 + tid * 16;
    // NOTE: per k-step packed bytes = 8 groups * 512 f16 * 2B = 8192B; kh offset = 32*8192 = 262144B.

    // fix kh byte offset (262144, not 524288)
    const char* bh2 = (const char*)whp + (size_t)kh * 262144 + tid * 16;
    const char* bl2 = (const char*)wlp + (size_t)kh * 262144 + tid * 16;

    // ---- A-frag read offsets (swizzled) ----
    int aoff[4][2];
    #pragma unroll
    for (int rf = 0; rf < 4; ++rf) {
        const int r6 = rf * 16 + idx;     // row within 64-row region
        #pragma unroll
        for (int j = 0; j < 2; ++j)
            aoff[rf][j] = rg * 8192 + r6 * 128 + (((2 * g + j) ^ (r6 & 7)) << 4);
    }
    int bhoff[2], bloff[2];
    #pragma unroll
    for (int cf = 0; cf < 2; ++cf) {
        bhoff[cf] = 16384 + (cg * 2 + cf) * 1024 + lane * 16;
        bloff[cf] = 24576 + (cg * 2 + cf) * 1024 + lane * 16;
    }

    f32x4 accm[4][2], accc[4][2];
    #pragma unroll
    for (int rf = 0; rf < 4; ++rf)
        #pragma unroll
        for (int cf = 0; cf < 2; ++cf) { accm[rf][cf] = (f32x4)0.0f; accc[rf][cf] = (f32x4)0.0f; }

    auto stage = [&](int u) {             // 4 DMA ops
        const int b = (u & (NBUF2 - 1)) * BUFSZ2;
        gload16(xs0 + u * 32,            smem + b + tid * 16);
        gload16(xs1 + u * 32,            smem + b + 8192 + tid * 16);
        gload16(bh2 + (size_t)u * 8192,  smem + b + 16384 + tid * 16);
        gload16(bl2 + (size_t)u * 8192,  smem + b + 24576 + tid * 16);
    };

    auto compute = [&](int t) {
        const int b = (t & (NBUF2 - 1)) * BUFSZ2;
        f16x8 Ah[4], Al[4];
        #pragma unroll
        for (int rf = 0; rf < 4; ++rf) {
            const float4 a0 = *reinterpret_cast<const float4*>(&smem[b + aoff[rf][0]]);
            const float4 a1 = *reinterpret_cast<const float4*>(&smem[b + aoff[rf][1]]);
            split8(a0, a1, Ah[rf], Al[rf]);
        }
        const f16x8 Bh0 = *reinterpret_cast<const f16x8*>(&smem[b + bhoff[0]]);
        const f16x8 Bh1 = *reinterpret_cast<const f16x8*>(&smem[b + bhoff[1]]);
        const f16x8 Bl0 = *reinterpret_cast<const f16x8*>(&smem[b + bloff[0]]);
        const f16x8 Bl1 = *reinterpret_cast<const f16x8*>(&smem[b + bloff[1]]);
        #pragma unroll
        for (int rf = 0; rf < 4; ++rf) {
            accm[rf][0] = __builtin_amdgcn_mfma_f32_16x16x32_f16(Ah[rf], Bh0, accm[rf][0], 0, 0, 0);
            accm[rf][1] = __builtin_amdgcn_mfma_f32_16x16x32_f16(Ah[rf], Bh1, accm[rf][1], 0, 0, 0);
            accc[rf][0] = __builtin_amdgcn_mfma_f32_16x16x32_f16(Al[rf], Bh0, accc[rf][0], 0, 0, 0);
            accc[rf][1] = __builtin_amdgcn_mfma_f32_16x16x32_f16(Al[rf], Bh1, accc[rf][1], 0, 0, 0);
            accc[rf][0] = __builtin_amdgcn_mfma_f32_16x16x32_f16(Ah[rf], Bl0, accc[rf][0], 0, 0, 0);
            accc[rf][1] = __builtin_amdgcn_mfma_f32_16x16x32_f16(Ah[rf], Bl1, accc[rf][1], 0, 0, 0);
        }
    };

    // ---- prologue ----
    stage(0);
    stage(1);
    // ---- main loop: counted vmcnt(8) = 2 iters x 4 DMA in flight ----
    for (int t = 0; t < NKS2 - 2; ++t) {
        stage(t + 2);
        asm volatile("s_waitcnt vmcnt(8)" ::: "memory");
        __builtin_amdgcn_s_barrier();
        __builtin_amdgcn_sched_barrier(0);
        compute(t);
    }
    asm volatile("s_waitcnt vmcnt(4)" ::: "memory");
    __builtin_amdgcn_s_barrier();
    __builtin_amdgcn_sched_barrier(0);
    compute(NKS2 - 2);
    asm volatile("s_waitcnt vmcnt(0)" ::: "memory");
    __builtin_amdgcn_s_barrier();
    __builtin_amdgcn_sched_barrier(0);
    compute(NKS2 - 1);

    // ---- write partial logits (f32), hi+lo combined ----
    float* dst = pbuf + (size_t)kh * NROWS * 128;
    #pragma unroll
    for (int rf = 0; rf < 4; ++rf)
        #pragma unroll
        for (int cf = 0; cf < 2; ++cf) {
            const int col = cg * 32 + cf * 16 + idx;
            #pragma unroll
            for (int q = 0; q < 4; ++q) {
                const int lrow = rg * 64 + rf * 16 + g * 4 + q;
                dst[(size_t)(row_base + lrow) * 128 + col] =
                    accm[rf][cf][q] + accc[rf][cf][q] * 4.8828125e-4f;
            }
        }
}

// ---------- kernel 3: reduce halves + softplus/noise/top-2/softmax ----------
__global__ __launch_bounds__(256) void reduce_topk_kernel(
    const float* __restrict__ pbuf,
    const float* __restrict__ noise,
    float* __restrict__ out)
{
    const int tid = threadIdx.x;
    const int row = tid >> 3;
    const int j   = tid & 7;
    const int e0  = j * 8;
    const int grow = blockIdx.x * 32 + row;

    const float* p0 = pbuf + (size_t)grow * 128;
    const float* p1 = pbuf + (size_t)(NROWS + grow) * 128;

    float4 c0 = *reinterpret_cast<const float4*>(&p0[e0]);
    float4 c1 = *reinterpret_cast<const float4*>(&p0[e0 + 4]);
    float4 s0 = *reinterpret_cast<const float4*>(&p0[64 + e0]);
    float4 s1 = *reinterpret_cast<const float4*>(&p0[64 + e0 + 4]);
    const float4 d0 = *reinterpret_cast<const float4*>(&p1[e0]);
    const float4 d1 = *reinterpret_cast<const float4*>(&p1[e0 + 4]);
    const float4 t0 = *reinterpret_cast<const float4*>(&p1[64 + e0]);
    const float4 t1 = *reinterpret_cast<const float4*>(&p1[64 + e0 + 4]);
    c0.x += d0.x; c0.y += d0.y; c0.z += d0.z; c0.w += d0.w;
    c1.x += d1.x; c1.y += d1.y; c1.z += d1.z; c1.w += d1.w;
    s0.x += t0.x; s0.y += t0.y; s0.z += t0.z; s0.w += t0.w;
    s1.x += t1.x; s1.y += t1.y; s1.z += t1.z; s1.w += t1.w;

    // clean logits out
    *reinterpret_cast<float4*>(&out[CLEAN_OFF + (size_t)grow * EDIM + e0])     = c0;
    *reinterpret_cast<float4*>(&out[CLEAN_OFF + (size_t)grow * EDIM + e0 + 4]) = c1;

    const float4 z0 = *reinterpret_cast<const float4*>(&noise[(size_t)grow * EDIM + e0]);
    const float4 z1 = *reinterpret_cast<const float4*>(&noise[(size_t)grow * EDIM + e0 + 4]);

    float nv[8];
    nv[0] = fmaf(softplus_f(s0.x), z0.x, c0.x);
    nv[1] = fmaf(softplus_f(s0.y), z0.y, c0.y);
    nv[2] = fmaf(softplus_f(s0.z), z0.z, c0.z);
    nv[3] = fmaf(softplus_f(s0.w), z0.w, c0.w);
    nv[4] = fmaf(softplus_f(s1.x), z1.x, c1.x);
    nv[5] = fmaf(softplus_f(s1.y), z1.y, c1.y);
    nv[6] = fmaf(softplus_f(s1.z), z1.z, c1.z);
    nv[7] = fmaf(softplus_f(s1.w), z1.w, c1.w);

    float v0 = nv[0], v1 = -INFINITY;
    int   i0 = e0,    i1 = -1;
    #pragma unroll
    for (int m = 1; m < 8; ++m) {
        const float v = nv[m]; const int e = e0 + m;
        if (v > v0)      { v1 = v0; i1 = i0; v0 = v; i0 = e; }
        else if (v > v1) { v1 = v;  i1 = e; }
    }
    #pragma unroll
    for (int d = 1; d < 8; d <<= 1) {
        const float ov0 = __shfl_xor(v0, d); const int oi0 = __shfl_xor(i0, d);
        const float ov1 = __shfl_xor(v1, d); const int oi1 = __shfl_xor(i1, d);
        const bool aFirst = (v0 > ov0) || (v0 == ov0 && i0 < oi0);
        float n0, n1; int ni0, ni1;
        if (aFirst) {
            n0 = v0; ni0 = i0;
            const bool s = (v1 > ov0) || (v1 == ov0 && i1 < oi0);
            n1 = s ? v1 : ov0; ni1 = s ? i1 : oi0;
        } else {
            n0 = ov0; ni0 = oi0;
            const bool s = (ov1 > v0) || (ov1 == v0 && oi1 < i0);
            n1 = s ? ov1 : v0; ni1 = s ? oi1 : i0;
        }
        v0 = n0; i0 = ni0; v1 = n1; i1 = ni1;
    }
    if (j == 0) {
        const float ex = expf(v1 - v0);
        const float w0 = 1.0f / (1.0f + ex);
        const float w1 = 1.0f - w0;
        out[(size_t)grow * 2 + 0] = w0;
        out[(size_t)grow * 2 + 1] = w1;
        out[IDX_OFF + (size_t)grow * 2 + 0] = (float)i0;
        out[IDX_OFF + (size_t)grow * 2 + 1] = (float)i1;
    }
}

extern "C" void kernel_launch(void* const* d_in, const int* in_sizes, int n_in,
                              void* d_out, int out_size, void* d_ws, size_t ws_size,
                              hipStream_t stream) {
    const float* x     = (const float*)d_in[0];
    const float* Wg    = (const float*)d_in[1];
    const float* Wn    = (const float*)d_in[2];
    const float* noise = (const float*)d_in[3];
    float* out = (float*)d_out;

    _Float16* wh = (_Float16*)d_ws;
    _Float16* wl = wh + WPACK;                                  // +512KB
    float* pbuf  = (float*)((char*)d_ws + (1 << 20));           // 16MB partials @1MB

    split_w_kernel<<<dim3(128), dim3(256), 0, stream>>>(Wg, Wn, wh, wl);
    gemm_part_kernel<<<dim3(256), dim3(512), NBUF2 * BUFSZ2, stream>>>(x, wh, wl, pbuf);
    reduce_topk_kernel<<<dim3(NROWS / 32), dim3(256), 0, stream>>>(pbuf, noise, out);
}